// Round 1
// baseline (857.901 us; speedup 1.0000x reference)
//
#include <hip/hip_runtime.h>

#define N 8192
#define BATCH 8

// Build X0[j][col] (col = 2*b + c; c=0 input, c=1 hidden) and transposed X0T[col][j].
__global__ __launch_bounds__(256) void pack_x0_kernel(
    const float* __restrict__ input, const float* __restrict__ hidden,
    float* __restrict__ x0, float* __restrict__ x0t) {
  int j = blockIdx.x * 256 + threadIdx.x;
  #pragma unroll
  for (int b = 0; b < BATCH; ++b) {
    float vi = input[(size_t)b * N + j];
    float vh = hidden[(size_t)b * N + j];
    x0[(size_t)j * 16 + 2 * b]     = vi;
    x0[(size_t)j * 16 + 2 * b + 1] = vh;
    x0t[(size_t)(2 * b) * N + j]     = vi;
    x0t[(size_t)(2 * b + 1) * N + j] = vh;
  }
}

// Y[i][c] = alpha * sum_j Km[i][j] * XT[c][j]  (+ beta * Xsub[i][c] if Xsub)
// Also writes YT[c][i] if YT != null (transposed copy for the next pass's RHS).
// Block: 256 threads = 4 waves; each wave owns 4 rows; lanes split j with
// float4 coalesced loads; LDS transpose reduction (pad 33, conflict-free).
__global__ __launch_bounds__(256) void gemm16_kernel(
    const float* __restrict__ Km, const float* __restrict__ XT,
    const float* __restrict__ Xsub,
    float* __restrict__ Y, float* __restrict__ YT,
    float alpha, float beta) {
  __shared__ float red[256 * 33];
  const int wave = threadIdx.x >> 6;
  const int lane = threadIdx.x & 63;
  const int i0 = blockIdx.x * 16 + wave * 4;

  float acc[4][16];
  #pragma unroll
  for (int r = 0; r < 4; ++r)
    #pragma unroll
    for (int c = 0; c < 16; ++c) acc[r][c] = 0.f;

  for (int m = 0; m < 32; ++m) {
    int j = (m * 64 + lane) * 4;
    float4 kf[4];
    #pragma unroll
    for (int r = 0; r < 4; ++r)
      kf[r] = *(const float4*)(Km + (size_t)(i0 + r) * N + j);
    #pragma unroll
    for (int c = 0; c < 16; ++c) {
      float4 x = *(const float4*)(XT + (size_t)c * N + j);
      #pragma unroll
      for (int r = 0; r < 4; ++r) {
        acc[r][c] = fmaf(kf[r].x, x.x, acc[r][c]);
        acc[r][c] = fmaf(kf[r].y, x.y, acc[r][c]);
        acc[r][c] = fmaf(kf[r].z, x.z, acc[r][c]);
        acc[r][c] = fmaf(kf[r].w, x.w, acc[r][c]);
      }
    }
  }

  // Cross-lane reduction: two passes of 32 accumulators through LDS.
  float total = 0.f;
  #pragma unroll
  for (int r = 0; r < 2; ++r)
    #pragma unroll
    for (int c = 0; c < 16; ++c)
      red[threadIdx.x * 33 + r * 16 + c] = acc[r][c];
  __syncthreads();
  if (lane < 32) {
    float s = 0.f;
    #pragma unroll
    for (int lp = 0; lp < 64; ++lp)
      s += red[(wave * 64 + lp) * 33 + lane];
    total = s;
  }
  __syncthreads();
  #pragma unroll
  for (int r = 0; r < 2; ++r)
    #pragma unroll
    for (int c = 0; c < 16; ++c)
      red[threadIdx.x * 33 + r * 16 + c] = acc[r + 2][c];
  __syncthreads();
  if (lane >= 32) {
    float s = 0.f;
    #pragma unroll
    for (int lp = 0; lp < 64; ++lp)
      s += red[(wave * 64 + lp) * 33 + (lane - 32)];
    total = s;
  }

  const int r = lane >> 4, c = lane & 15;
  const int row = i0 + r;
  float v = alpha * total;
  if (Xsub) v += beta * Xsub[(size_t)row * 16 + c];
  Y[(size_t)row * 16 + c] = v;
  if (YT) YT[(size_t)c * N + row] = v;
}

// Bug-compatible .view gather + Linear(10->1).
// out[b2][i] = b + sum_{c2,k} W[c2*5+k] * Xk[(i&1023)*8 + c2*4 + (b2>>1)][2*(i>>10) + (b2&1)]
__global__ __launch_bounds__(256) void out_kernel(
    const float* __restrict__ X0, const float* __restrict__ X1a,
    const float* __restrict__ X2a, const float* __restrict__ X1b,
    const float* __restrict__ X2b, const float* __restrict__ W,
    const float* __restrict__ bias, float* __restrict__ out) {
  int tid = blockIdx.x * 256 + threadIdx.x;
  int b2 = tid >> 13;
  int i  = tid & (N - 1);
  int col = 2 * (i >> 10) + (b2 & 1);
  const float* Xs[5] = {X0, X1a, X2a, X1b, X2b};
  float accv = bias[0];
  #pragma unroll
  for (int c2 = 0; c2 < 2; ++c2) {
    int n = (i & 1023) * 8 + c2 * 4 + (b2 >> 1);
    #pragma unroll
    for (int k = 0; k < 5; ++k)
      accv += W[c2 * 5 + k] * Xs[k][(size_t)n * 16 + col];
  }
  out[tid] = accv;
}

extern "C" void kernel_launch(void* const* d_in, const int* in_sizes, int n_in,
                              void* d_out, int out_size, void* d_ws, size_t ws_size,
                              hipStream_t stream) {
  const float* input  = (const float*)d_in[0];
  const float* hidden = (const float*)d_in[1];
  const float* k0     = (const float*)d_in[2];
  const float* k1     = (const float*)d_in[3];
  const float* W      = (const float*)d_in[4];
  const float* bias   = (const float*)d_in[5];
  float* out = (float*)d_out;

  float* ws = (float*)d_ws;
  const size_t SZ = (size_t)N * 16;
  float* X0   = ws;
  float* X0T  = ws + SZ;
  float* X1a  = ws + 2 * SZ;
  float* X1aT = ws + 3 * SZ;
  float* X2a  = ws + 4 * SZ;
  float* X1b  = ws + 5 * SZ;
  float* X1bT = ws + 6 * SZ;
  float* X2b  = ws + 7 * SZ;

  pack_x0_kernel<<<N / 256, 256, 0, stream>>>(input, hidden, X0, X0T);
  // kernel0: X1a = K0 @ X0 ; X2a = 2*K0 @ X1a - X0
  gemm16_kernel<<<N / 16, 256, 0, stream>>>(k0, X0T,  nullptr, X1a, X1aT, 1.f, 0.f);
  gemm16_kernel<<<N / 16, 256, 0, stream>>>(k0, X1aT, X0,      X2a, nullptr, 2.f, -1.f);
  // kernel1: X1b = K1 @ X0 ; X2b = 2*K1 @ X1b - X0
  gemm16_kernel<<<N / 16, 256, 0, stream>>>(k1, X0T,  nullptr, X1b, X1bT, 1.f, 0.f);
  gemm16_kernel<<<N / 16, 256, 0, stream>>>(k1, X1bT, X0,      X2b, nullptr, 2.f, -1.f);

  out_kernel<<<(BATCH * N) / 256, 256, 0, stream>>>(X0, X1a, X2a, X1b, X2b, W, bias, out);
}

// Round 2
// 662.501 us; speedup vs baseline: 1.2949x; 1.2949x over previous
//
#include <hip/hip_runtime.h>

#define N 8192
#define BATCH 8
#define CJ 256
#define NITER (N / CJ)

// Build X0[j][col] (col = 2*b + c) and transposed X0T[col][j].
__global__ __launch_bounds__(256) void pack_x0_kernel(
    const float* __restrict__ input, const float* __restrict__ hidden,
    float* __restrict__ x0, float* __restrict__ x0t) {
  int j = blockIdx.x * 256 + threadIdx.x;
  #pragma unroll
  for (int b = 0; b < BATCH; ++b) {
    float vi = input[(size_t)b * N + j];
    float vh = hidden[(size_t)b * N + j];
    x0[(size_t)j * 16 + 2 * b]     = vi;
    x0[(size_t)j * 16 + 2 * b + 1] = vh;
    x0t[(size_t)(2 * b) * N + j]     = vi;
    x0t[(size_t)(2 * b + 1) * N + j] = vh;
  }
}

// Y[i][c] = alpha * sum_j Km[i][j] * XT[c][j]  (+ beta * Xsub[i][c])
// 256 threads = 4 waves; wave owns 4 rows; lanes split j (float4 coalesced).
// X chunk (16 x 256) staged to LDS via global_load_lds (async, width=16),
// double-buffered; K prefetched one chunk ahead into registers.
__global__ __launch_bounds__(256) void gemm16_kernel(
    const float* __restrict__ Km, const float* __restrict__ XT,
    const float* __restrict__ Xsub,
    float* __restrict__ Y, float* __restrict__ YT,
    float alpha, float beta) {
  __shared__ float Xs[2][16][CJ];
  __shared__ float red[256 * 33];
  const int wave = threadIdx.x >> 6;
  const int lane = threadIdx.x & 63;
  const int jl = lane * 4;
  const int i0 = blockIdx.x * 16 + wave * 4;   // this wave's first row

  float acc[4][16];
  #pragma unroll
  for (int r = 0; r < 4; ++r)
    #pragma unroll
    for (int c = 0; c < 16; ++c) acc[r][c] = 0.f;

  // Stage chunk 0: each wave async-copies 4 X columns (1 KB each) to LDS.
  #pragma unroll
  for (int c2 = 0; c2 < 4; ++c2) {
    int c = c2 * 4 + wave;
    const float* gp = XT + (size_t)c * N + jl;
    __builtin_amdgcn_global_load_lds(
        (__attribute__((address_space(1))) void*)gp,
        (__attribute__((address_space(3))) void*)&Xs[0][c][0], 16, 0, 0);
  }
  float4 kfA[4], kfB[4];
  #pragma unroll
  for (int r = 0; r < 4; ++r)
    kfA[r] = *(const float4*)(Km + (size_t)(i0 + r) * N + jl);
  __syncthreads();

  int p = 0;
  for (int m = 0; m < NITER; ++m) {
    // Prefetch chunk m+1 (async LDS stage + K regs) before computing chunk m.
    if (m + 1 < NITER) {
      int jn = (m + 1) * CJ + jl;
      #pragma unroll
      for (int c2 = 0; c2 < 4; ++c2) {
        int c = c2 * 4 + wave;
        const float* gp = XT + (size_t)c * N + jn;
        __builtin_amdgcn_global_load_lds(
            (__attribute__((address_space(1))) void*)gp,
            (__attribute__((address_space(3))) void*)&Xs[p ^ 1][c][0], 16, 0, 0);
      }
      #pragma unroll
      for (int r = 0; r < 4; ++r)
        kfB[r] = *(const float4*)(Km + (size_t)(i0 + r) * N + jn);
    }
    #pragma unroll
    for (int c = 0; c < 16; ++c) {
      float4 x = *(const float4*)&Xs[p][c][jl];
      #pragma unroll
      for (int r = 0; r < 4; ++r) {
        acc[r][c] = fmaf(kfA[r].x, x.x, acc[r][c]);
        acc[r][c] = fmaf(kfA[r].y, x.y, acc[r][c]);
        acc[r][c] = fmaf(kfA[r].z, x.z, acc[r][c]);
        acc[r][c] = fmaf(kfA[r].w, x.w, acc[r][c]);
      }
    }
    __syncthreads();  // drains vmcnt: chunk m+1 LDS stage + kfB complete
    if (m + 1 < NITER) {
      #pragma unroll
      for (int r = 0; r < 4; ++r) kfA[r] = kfB[r];
    }
    p ^= 1;
  }

  // Cross-lane reduction: two passes of 32 accumulators through LDS (pad 33).
  float total = 0.f;
  #pragma unroll
  for (int r = 0; r < 2; ++r)
    #pragma unroll
    for (int c = 0; c < 16; ++c)
      red[threadIdx.x * 33 + r * 16 + c] = acc[r][c];
  __syncthreads();
  if (lane < 32) {
    float s = 0.f;
    #pragma unroll
    for (int lp = 0; lp < 64; ++lp)
      s += red[(wave * 64 + lp) * 33 + lane];
    total = s;
  }
  __syncthreads();
  #pragma unroll
  for (int r = 0; r < 2; ++r)
    #pragma unroll
    for (int c = 0; c < 16; ++c)
      red[threadIdx.x * 33 + r * 16 + c] = acc[r + 2][c];
  __syncthreads();
  if (lane >= 32) {
    float s = 0.f;
    #pragma unroll
    for (int lp = 0; lp < 64; ++lp)
      s += red[(wave * 64 + lp) * 33 + (lane - 32)];
    total = s;
  }

  const int r = lane >> 4, c = lane & 15;
  const int row = i0 + r;   // i0 already includes wave*4
  float v = alpha * total;
  if (Xsub) v += beta * Xsub[(size_t)row * 16 + c];
  Y[(size_t)row * 16 + c] = v;
  if (YT) YT[(size_t)c * N + row] = v;
}

// Bug-compatible .view gather + Linear(10->1).
__global__ __launch_bounds__(256) void out_kernel(
    const float* __restrict__ X0, const float* __restrict__ X1a,
    const float* __restrict__ X2a, const float* __restrict__ X1b,
    const float* __restrict__ X2b, const float* __restrict__ W,
    const float* __restrict__ bias, float* __restrict__ out) {
  int tid = blockIdx.x * 256 + threadIdx.x;
  int b2 = tid >> 13;
  int i  = tid & (N - 1);
  int col = 2 * (i >> 10) + (b2 & 1);
  const float* Xs[5] = {X0, X1a, X2a, X1b, X2b};
  float accv = bias[0];
  #pragma unroll
  for (int c2 = 0; c2 < 2; ++c2) {
    int n = (i & 1023) * 8 + c2 * 4 + (b2 >> 1);
    #pragma unroll
    for (int k = 0; k < 5; ++k)
      accv += W[c2 * 5 + k] * Xs[k][(size_t)n * 16 + col];
  }
  out[tid] = accv;
}

extern "C" void kernel_launch(void* const* d_in, const int* in_sizes, int n_in,
                              void* d_out, int out_size, void* d_ws, size_t ws_size,
                              hipStream_t stream) {
  const float* input  = (const float*)d_in[0];
  const float* hidden = (const float*)d_in[1];
  const float* k0     = (const float*)d_in[2];
  const float* k1     = (const float*)d_in[3];
  const float* W      = (const float*)d_in[4];
  const float* bias   = (const float*)d_in[5];
  float* out = (float*)d_out;

  float* ws = (float*)d_ws;
  const size_t SZ = (size_t)N * 16;
  float* X0   = ws;
  float* X0T  = ws + SZ;
  float* X1a  = ws + 2 * SZ;
  float* X1aT = ws + 3 * SZ;
  float* X2a  = ws + 4 * SZ;
  float* X1b  = ws + 5 * SZ;
  float* X1bT = ws + 6 * SZ;
  float* X2b  = ws + 7 * SZ;

  pack_x0_kernel<<<N / 256, 256, 0, stream>>>(input, hidden, X0, X0T);
  gemm16_kernel<<<N / 16, 256, 0, stream>>>(k0, X0T,  nullptr, X1a, X1aT, 1.f, 0.f);
  gemm16_kernel<<<N / 16, 256, 0, stream>>>(k0, X1aT, X0,      X2a, nullptr, 2.f, -1.f);
  gemm16_kernel<<<N / 16, 256, 0, stream>>>(k1, X0T,  nullptr, X1b, X1bT, 1.f, 0.f);
  gemm16_kernel<<<N / 16, 256, 0, stream>>>(k1, X1bT, X0,      X2b, nullptr, 2.f, -1.f);

  out_kernel<<<(BATCH * N) / 256, 256, 0, stream>>>(X0, X1a, X2a, X1b, X2b, W, bias, out);
}